// Round 11
// baseline (76.751 us; speedup 1.0000x reference)
//
#include <hip/hip_runtime.h>

// Persistent-wave, double-buffered, full-MFMA batched block-diagonal MLP.
// Round-11 = round-8/10 structure (verified 67.3/67.6us) with ONE change:
// plain vector stores instead of __builtin_nontemporal_store. Counter
// evidence: nt stores showed WRITE_SIZE 117-120MB vs 101MB ideal (+18%
// write amplification from partial-line HBM flushes of 16B fragments);
// plain stores let L2 assemble the wave's contiguous 1536B span into full
// lines (rounds 1-3,6 all measured ~101MB with plain stores).
//
// 1024 blocks; each wave owns 8 tiles of 32 rows. Weights load ONCE from
// a repacked f16 fragment buffer (tiny pre-kernel, graph node ~free).
// LDS double-buffer (2 x 8KB per wave): stage tiles 0,1; per iteration wait
// a COUNTED vmcnt (8 first / 12 steady / 4 last; per tile = 8 stage loads +
// 4 store instrs, vmcnt retires in issue order), ds_read tile i, lgkmcnt(0),
// then stage tile i+2 into the freed buffer. Staging loads stay in flight
// across compute; vmcnt never drains to 0 in steady state.
//
// Staging: global_load_lds width 16, linear LDS dst, PRE-SWIZZLED global
// source (granule gs = (lane&15) ^ (r&7)); fragment ds_read_b128 at granule
// (2g+8s+h)^(b&7) -> <=2-way bank alias (free).
// Compute: all-f16 MFMA, transposed chaining (C rows 4g+q == next layer's
// B k-elems 4g+j), relu + f32->f16 cvt in-lane only.

typedef _Float16 f16;
typedef __attribute__((ext_vector_type(4))) _Float16 f16x4;
typedef __attribute__((ext_vector_type(8))) _Float16 f16x8;
typedef __attribute__((ext_vector_type(4))) float f32x4;

#define WS_WH  2048
#define WS_WO  6144
#define WS_TOT 7168

#define WAITV(N) asm volatile("s_waitcnt vmcnt(" #N ")" ::: "memory")

// ---- repack: weights -> per-lane MFMA A-fragments (masked, f16) ----
__global__ void repack_kernel(const float* __restrict__ Win,   // [64][32]
                              const float* __restrict__ Wh,    // [4][32][32]
                              const float* __restrict__ Wout,  // [32][24]
                              f16* __restrict__ ws)
{
    int i = blockIdx.x * 256 + threadIdx.x;
    if (i >= WS_TOT) return;
    float val;
    if (i < WS_WH) {
        int fi = i >> 9, rest = i & 511;
        int l = rest >> 3, j = rest & 7;
        int h = fi >> 1, s = fi & 1;
        int g = l >> 4, m = l & 15;
        int k = 32 * s + 8 * g + j;
        val = Win[k * 32 + 16 * h + m];
    } else if (i < WS_WO) {
        int t2 = i - WS_WH;
        int fi = t2 >> 8, rest = t2 & 255;
        int l = rest >> 2, j = rest & 3;
        int t = fi >> 2, h = (fi >> 1) & 1, s = fi & 1;
        int g = l >> 4, m = l & 15;
        int k = 16 * s + 4 * g + j, col = 16 * h + m;
        val = ((k >> 3) == (col >> 3)) ? Wh[t * 1024 + k * 32 + col] : 0.f;
    } else {
        int t2 = i - WS_WO;
        int fi = t2 >> 8, rest = t2 & 255;
        int l = rest >> 2, j = rest & 3;
        int h = fi >> 1, s = fi & 1;
        int g = l >> 4, m = l & 15;
        int k = 16 * s + 4 * g + j, col = 16 * h + m;
        val = (col < 24 && (k >> 2) == (col / 3)) ? Wout[k * 24 + col] : 0.f;
    }
    ws[i] = (f16)val;
}

__global__ __launch_bounds__(256, 2)
void bd_mlp_kernel(const float* __restrict__ x,
                   const f16* __restrict__ ws,
                   const float* __restrict__ Win,
                   const float* __restrict__ Wh,
                   const float* __restrict__ Wout,
                   float* __restrict__ out,
                   int B)
{
    __shared__ __align__(16) float lds[4][2][2048];   // 2 x 8KB per wave

    const int tid  = threadIdx.x;
    const int wid  = tid >> 6;
    const int lane = tid & 63;
    const int g    = lane >> 4;
    const int b    = lane & 15;

    const int wave_id = blockIdx.x * 4 + wid;
    const int nwaves  = gridDim.x * 4;
    const int ntiles  = B >> 5;               // 32-row tiles

    // ---- weight fragments, loaded once (L2-resident) ----
    f16x8 wina[2][2];
#pragma unroll
    for (int h = 0; h < 2; ++h)
#pragma unroll
        for (int s = 0; s < 2; ++s)
            wina[h][s] = __builtin_bit_cast(f16x8,
                *reinterpret_cast<const f32x4*>(
                    ws + (h * 2 + s) * 512 + lane * 8));

    f16x4 wha[4][2][2];
#pragma unroll
    for (int t = 0; t < 4; ++t)
#pragma unroll
        for (int h = 0; h < 2; ++h)
#pragma unroll
            for (int s = 0; s < 2; ++s)
                wha[t][h][s] = __builtin_bit_cast(f16x4,
                    *reinterpret_cast<const float2*>(
                        ws + WS_WH + (t * 4 + h * 2 + s) * 256 + lane * 4));

    f16x4 woa[2][2];
#pragma unroll
    for (int h = 0; h < 2; ++h)
#pragma unroll
        for (int s = 0; s < 2; ++s)
            woa[h][s] = __builtin_bit_cast(f16x4,
                *reinterpret_cast<const float2*>(
                    ws + WS_WO + (h * 2 + s) * 256 + lane * 4));

    const f32x4 zero = {0.f, 0.f, 0.f, 0.f};

    int nt = 0;
    if (wave_id < ntiles) nt = (ntiles - wave_id - 1) / nwaves + 1;

    auto STAGE = [&](int bufi, int tile) {
        float* tb = &lds[wid][bufi][0];
        const int rowbase = tile << 5;
#pragma unroll
        for (int j = 0; j < 8; ++j) {
            const int r  = 4 * j + (lane >> 4);
            const int gs = (lane & 15) ^ (r & 7);
            const float* src = x + (size_t)(rowbase + r) * 64 + gs * 4;
            __builtin_amdgcn_global_load_lds(
                (const __attribute__((address_space(1))) void*)src,
                (__attribute__((address_space(3))) void*)(tb + j * 256),
                16, 0, 0);
        }
    };

    if (nt > 0) {
        STAGE(0, wave_id);
        if (nt > 1) STAGE(1, wave_id + nwaves);

        for (int i = 0; i < nt; ++i) {
            // counted waits: per tile = 8 stage loads + 4 store instrs,
            // vmcnt retires in issue order (m135).
            if (i == 0)           { if (nt > 1) WAITV(8); else WAITV(0); }
            else if (i + 1 == nt) WAITV(4);
            else                  WAITV(12);
            __builtin_amdgcn_sched_barrier(0);

            const float* tb = &lds[wid][i & 1][0];
            const int rowbase = (wave_id + i * nwaves) << 5;

            // all fragment reads for this tile (must precede re-stage)
            f32x4 raw[2][2][2];
#pragma unroll
            for (int c = 0; c < 2; ++c)
#pragma unroll
                for (int s = 0; s < 2; ++s)
#pragma unroll
                    for (int hh = 0; hh < 2; ++hh)
                        raw[c][s][hh] = *reinterpret_cast<const f32x4*>(
                            tb + (16 * c + b) * 64 +
                            4 * ((2 * g + 8 * s + hh) ^ (b & 7)));
            asm volatile("s_waitcnt lgkmcnt(0)" ::: "memory");
            __builtin_amdgcn_sched_barrier(0);

            if (i + 2 < nt) STAGE(i & 1, wave_id + (i + 2) * nwaves);

#pragma unroll
            for (int c = 0; c < 2; ++c) {
                f16x8 bx[2];
#pragma unroll
                for (int s = 0; s < 2; ++s) {
                    f32x4 u0 = raw[c][s][0];
                    f32x4 u1 = raw[c][s][1];
                    f16x8 v;
                    v[0] = (f16)u0[0]; v[1] = (f16)u0[1];
                    v[2] = (f16)u0[2]; v[3] = (f16)u0[3];
                    v[4] = (f16)u1[0]; v[5] = (f16)u1[1];
                    v[6] = (f16)u1[2]; v[7] = (f16)u1[3];
                    bx[s] = v;
                }

                // input layer
                f32x4 t0 = __builtin_amdgcn_mfma_f32_16x16x32_f16(
                    wina[0][0], bx[0], zero, 0, 0, 0);
                t0 = __builtin_amdgcn_mfma_f32_16x16x32_f16(
                    wina[0][1], bx[1], t0, 0, 0, 0);
                f32x4 t1 = __builtin_amdgcn_mfma_f32_16x16x32_f16(
                    wina[1][0], bx[0], zero, 0, 0, 0);
                t1 = __builtin_amdgcn_mfma_f32_16x16x32_f16(
                    wina[1][1], bx[1], t1, 0, 0, 0);

                f16x4 hb0, hb1;
#pragma unroll
                for (int j = 0; j < 4; ++j) {
                    hb0[j] = (f16)fmaxf(t0[j], 0.f);
                    hb1[j] = (f16)fmaxf(t1[j], 0.f);
                }

                // 4 block-diagonal hidden layers
#pragma unroll
                for (int t = 0; t < 4; ++t) {
                    f32x4 n0 = __builtin_amdgcn_mfma_f32_16x16x16f16(
                        wha[t][0][0], hb0, zero, 0, 0, 0);
                    n0 = __builtin_amdgcn_mfma_f32_16x16x16f16(
                        wha[t][0][1], hb1, n0, 0, 0, 0);
                    f32x4 n1 = __builtin_amdgcn_mfma_f32_16x16x16f16(
                        wha[t][1][0], hb0, zero, 0, 0, 0);
                    n1 = __builtin_amdgcn_mfma_f32_16x16x16f16(
                        wha[t][1][1], hb1, n1, 0, 0, 0);
#pragma unroll
                    for (int j = 0; j < 4; ++j) {
                        hb0[j] = (f16)fmaxf(n0[j], 0.f);
                        hb1[j] = (f16)fmaxf(n1[j], 0.f);
                    }
                }

                // output layer + plain vector store (L2 write-combines the
                // wave's contiguous 1536B span into full lines)
                f32x4 o0 = __builtin_amdgcn_mfma_f32_16x16x16f16(
                    woa[0][0], hb0, zero, 0, 0, 0);
                o0 = __builtin_amdgcn_mfma_f32_16x16x16f16(
                    woa[0][1], hb1, o0, 0, 0, 0);
                f32x4 o1 = __builtin_amdgcn_mfma_f32_16x16x16f16(
                    woa[1][0], hb0, zero, 0, 0, 0);
                o1 = __builtin_amdgcn_mfma_f32_16x16x16f16(
                    woa[1][1], hb1, o1, 0, 0, 0);

                float* op = out + (size_t)(rowbase + 16 * c + b) * 24;
                *reinterpret_cast<f32x4*>(op + 4 * g) = o0;
                if (g < 2) {
                    *reinterpret_cast<f32x4*>(op + 16 + 4 * g) = o1;
                }
            }
        }
    }

    // ---- tail rows (B % 32 != 0; unused for B = 1M) ----
    if (blockIdx.x == 0 && wid == 0) {
        for (int row = (ntiles << 5) + lane; row < B; row += 64) {
            float h[32];
#pragma unroll
            for (int j = 0; j < 32; ++j) h[j] = 0.f;
            const float* __restrict__ xr = x + (size_t)row * 64;
            for (int k = 0; k < 64; ++k) {
                float xv = xr[k];
#pragma unroll
                for (int j = 0; j < 32; ++j)
                    h[j] = fmaf(xv, Win[k * 32 + j], h[j]);
            }
#pragma unroll
            for (int j = 0; j < 32; ++j) h[j] = fmaxf(h[j], 0.f);
            for (int t = 0; t < 4; ++t) {
                float hn[32];
                for (int j = 0; j < 32; ++j) {
                    float acc = 0.f;
                    int blk = j >> 3;
                    for (int k = 0; k < 8; ++k)
                        acc = fmaf(h[blk * 8 + k],
                                   Wh[t * 1024 + (blk * 8 + k) * 32 + j], acc);
                    hn[j] = fmaxf(acc, 0.f);
                }
                for (int j = 0; j < 32; ++j) h[j] = hn[j];
            }
            for (int cth = 0; cth < 24; ++cth) {
                int i8 = cth / 3;
                float acc = 0.f;
                for (int s = 0; s < 4; ++s)
                    acc = fmaf(h[4 * i8 + s], Wout[(4 * i8 + s) * 24 + cth], acc);
                out[(size_t)row * 24 + cth] = acc;
            }
        }
    }
}

extern "C" void kernel_launch(void* const* d_in, const int* in_sizes, int n_in,
                              void* d_out, int out_size, void* d_ws, size_t ws_size,
                              hipStream_t stream)
{
    const float* x    = (const float*)d_in[0];  // [B,64]
    const float* Win  = (const float*)d_in[1];  // [64,32]
    const float* Wh   = (const float*)d_in[2];  // [4,32,32]
    const float* Wout = (const float*)d_in[3];  // [32,24]
    float* out        = (float*)d_out;          // [B,24]
    f16* ws           = (f16*)d_ws;

    int B = in_sizes[0] / 64;

    repack_kernel<<<(WS_TOT + 255) / 256, 256, 0, stream>>>(Win, Wh, Wout, ws);

    bd_mlp_kernel<<<1024, 256, 0, stream>>>(x, ws, Win, Wh, Wout, out, B);
}

// Round 12
// 67.182 us; speedup vs baseline: 1.1424x; 1.1424x over previous
//
#include <hip/hip_runtime.h>

// Persistent-wave, double-buffered, full-MFMA batched block-diagonal MLP.
// FINAL = round-8/10 structure (verified 67.3/67.6us best).
// Ledger of tested-and-rejected alternatives:
//   - plain stores instead of nontemporal: 76.8us (L2 write-allocate/RFO
//     taxes the read stream more than nt's +16MB partial-sector writes)
//   - in-kernel weight gather (no repack pre-kernel): 72.3us (startup
//     gather congestion delays every wave's first tile)
//   - one-shot blocks, no pipeline: 90.3us (latency-bound)
//   - direct strided fragment loads, no LDS: 93.0us
//   - fp32 VALU paths: 140-176us (instruction-stream-bound)
//
// 1024 blocks; each wave owns 8 tiles of 32 rows. Weights load ONCE from
// a repacked f16 fragment buffer (tiny pre-kernel, graph node ~free).
// LDS double-buffer (2 x 8KB per wave): stage tiles 0,1; per iteration wait
// a COUNTED vmcnt (8 first / 12 steady / 4 last; per tile = 8 stage loads +
// 4 store instrs, vmcnt retires in issue order), ds_read tile i, lgkmcnt(0),
// then stage tile i+2 into the freed buffer. Staging loads stay in flight
// across compute; vmcnt never drains to 0 in steady state.
//
// Staging: global_load_lds width 16, linear LDS dst, PRE-SWIZZLED global
// source (granule gs = (lane&15) ^ (r&7)); fragment ds_read_b128 at granule
// (2g+8s+h)^(b&7) -> <=2-way bank alias (free).
// Compute: all-f16 MFMA, transposed chaining (C rows 4g+q == next layer's
// B k-elems 4g+j), relu + f32->f16 cvt in-lane only.

typedef _Float16 f16;
typedef __attribute__((ext_vector_type(4))) _Float16 f16x4;
typedef __attribute__((ext_vector_type(8))) _Float16 f16x8;
typedef __attribute__((ext_vector_type(4))) float f32x4;

#define WS_WH  2048
#define WS_WO  6144
#define WS_TOT 7168

#define WAITV(N) asm volatile("s_waitcnt vmcnt(" #N ")" ::: "memory")

// ---- repack: weights -> per-lane MFMA A-fragments (masked, f16) ----
__global__ void repack_kernel(const float* __restrict__ Win,   // [64][32]
                              const float* __restrict__ Wh,    // [4][32][32]
                              const float* __restrict__ Wout,  // [32][24]
                              f16* __restrict__ ws)
{
    int i = blockIdx.x * 256 + threadIdx.x;
    if (i >= WS_TOT) return;
    float val;
    if (i < WS_WH) {
        int fi = i >> 9, rest = i & 511;
        int l = rest >> 3, j = rest & 7;
        int h = fi >> 1, s = fi & 1;
        int g = l >> 4, m = l & 15;
        int k = 32 * s + 8 * g + j;
        val = Win[k * 32 + 16 * h + m];
    } else if (i < WS_WO) {
        int t2 = i - WS_WH;
        int fi = t2 >> 8, rest = t2 & 255;
        int l = rest >> 2, j = rest & 3;
        int t = fi >> 2, h = (fi >> 1) & 1, s = fi & 1;
        int g = l >> 4, m = l & 15;
        int k = 16 * s + 4 * g + j, col = 16 * h + m;
        val = ((k >> 3) == (col >> 3)) ? Wh[t * 1024 + k * 32 + col] : 0.f;
    } else {
        int t2 = i - WS_WO;
        int fi = t2 >> 8, rest = t2 & 255;
        int l = rest >> 2, j = rest & 3;
        int h = fi >> 1, s = fi & 1;
        int g = l >> 4, m = l & 15;
        int k = 16 * s + 4 * g + j, col = 16 * h + m;
        val = (col < 24 && (k >> 2) == (col / 3)) ? Wout[k * 24 + col] : 0.f;
    }
    ws[i] = (f16)val;
}

__global__ __launch_bounds__(256, 2)
void bd_mlp_kernel(const float* __restrict__ x,
                   const f16* __restrict__ ws,
                   const float* __restrict__ Win,
                   const float* __restrict__ Wh,
                   const float* __restrict__ Wout,
                   float* __restrict__ out,
                   int B)
{
    __shared__ __align__(16) float lds[4][2][2048];   // 2 x 8KB per wave

    const int tid  = threadIdx.x;
    const int wid  = tid >> 6;
    const int lane = tid & 63;
    const int g    = lane >> 4;
    const int b    = lane & 15;

    const int wave_id = blockIdx.x * 4 + wid;
    const int nwaves  = gridDim.x * 4;
    const int ntiles  = B >> 5;               // 32-row tiles

    // ---- weight fragments, loaded once (L2-resident) ----
    f16x8 wina[2][2];
#pragma unroll
    for (int h = 0; h < 2; ++h)
#pragma unroll
        for (int s = 0; s < 2; ++s)
            wina[h][s] = __builtin_bit_cast(f16x8,
                *reinterpret_cast<const f32x4*>(
                    ws + (h * 2 + s) * 512 + lane * 8));

    f16x4 wha[4][2][2];
#pragma unroll
    for (int t = 0; t < 4; ++t)
#pragma unroll
        for (int h = 0; h < 2; ++h)
#pragma unroll
            for (int s = 0; s < 2; ++s)
                wha[t][h][s] = __builtin_bit_cast(f16x4,
                    *reinterpret_cast<const float2*>(
                        ws + WS_WH + (t * 4 + h * 2 + s) * 256 + lane * 4));

    f16x4 woa[2][2];
#pragma unroll
    for (int h = 0; h < 2; ++h)
#pragma unroll
        for (int s = 0; s < 2; ++s)
            woa[h][s] = __builtin_bit_cast(f16x4,
                *reinterpret_cast<const float2*>(
                    ws + WS_WO + (h * 2 + s) * 256 + lane * 4));

    const f32x4 zero = {0.f, 0.f, 0.f, 0.f};

    int nt = 0;
    if (wave_id < ntiles) nt = (ntiles - wave_id - 1) / nwaves + 1;

    auto STAGE = [&](int bufi, int tile) {
        float* tb = &lds[wid][bufi][0];
        const int rowbase = tile << 5;
#pragma unroll
        for (int j = 0; j < 8; ++j) {
            const int r  = 4 * j + (lane >> 4);
            const int gs = (lane & 15) ^ (r & 7);
            const float* src = x + (size_t)(rowbase + r) * 64 + gs * 4;
            __builtin_amdgcn_global_load_lds(
                (const __attribute__((address_space(1))) void*)src,
                (__attribute__((address_space(3))) void*)(tb + j * 256),
                16, 0, 0);
        }
    };

    if (nt > 0) {
        STAGE(0, wave_id);
        if (nt > 1) STAGE(1, wave_id + nwaves);

        for (int i = 0; i < nt; ++i) {
            // counted waits: per tile = 8 stage loads + 4 store instrs,
            // vmcnt retires in issue order (m135).
            if (i == 0)           { if (nt > 1) WAITV(8); else WAITV(0); }
            else if (i + 1 == nt) WAITV(4);
            else                  WAITV(12);
            __builtin_amdgcn_sched_barrier(0);

            const float* tb = &lds[wid][i & 1][0];
            const int rowbase = (wave_id + i * nwaves) << 5;

            // all fragment reads for this tile (must precede re-stage)
            f32x4 raw[2][2][2];
#pragma unroll
            for (int c = 0; c < 2; ++c)
#pragma unroll
                for (int s = 0; s < 2; ++s)
#pragma unroll
                    for (int hh = 0; hh < 2; ++hh)
                        raw[c][s][hh] = *reinterpret_cast<const f32x4*>(
                            tb + (16 * c + b) * 64 +
                            4 * ((2 * g + 8 * s + hh) ^ (b & 7)));
            asm volatile("s_waitcnt lgkmcnt(0)" ::: "memory");
            __builtin_amdgcn_sched_barrier(0);

            if (i + 2 < nt) STAGE(i & 1, wave_id + (i + 2) * nwaves);

#pragma unroll
            for (int c = 0; c < 2; ++c) {
                f16x8 bx[2];
#pragma unroll
                for (int s = 0; s < 2; ++s) {
                    f32x4 u0 = raw[c][s][0];
                    f32x4 u1 = raw[c][s][1];
                    f16x8 v;
                    v[0] = (f16)u0[0]; v[1] = (f16)u0[1];
                    v[2] = (f16)u0[2]; v[3] = (f16)u0[3];
                    v[4] = (f16)u1[0]; v[5] = (f16)u1[1];
                    v[6] = (f16)u1[2]; v[7] = (f16)u1[3];
                    bx[s] = v;
                }

                // input layer
                f32x4 t0 = __builtin_amdgcn_mfma_f32_16x16x32_f16(
                    wina[0][0], bx[0], zero, 0, 0, 0);
                t0 = __builtin_amdgcn_mfma_f32_16x16x32_f16(
                    wina[0][1], bx[1], t0, 0, 0, 0);
                f32x4 t1 = __builtin_amdgcn_mfma_f32_16x16x32_f16(
                    wina[1][0], bx[0], zero, 0, 0, 0);
                t1 = __builtin_amdgcn_mfma_f32_16x16x32_f16(
                    wina[1][1], bx[1], t1, 0, 0, 0);

                f16x4 hb0, hb1;
#pragma unroll
                for (int j = 0; j < 4; ++j) {
                    hb0[j] = (f16)fmaxf(t0[j], 0.f);
                    hb1[j] = (f16)fmaxf(t1[j], 0.f);
                }

                // 4 block-diagonal hidden layers
#pragma unroll
                for (int t = 0; t < 4; ++t) {
                    f32x4 n0 = __builtin_amdgcn_mfma_f32_16x16x16f16(
                        wha[t][0][0], hb0, zero, 0, 0, 0);
                    n0 = __builtin_amdgcn_mfma_f32_16x16x16f16(
                        wha[t][0][1], hb1, n0, 0, 0, 0);
                    f32x4 n1 = __builtin_amdgcn_mfma_f32_16x16x16f16(
                        wha[t][1][0], hb0, zero, 0, 0, 0);
                    n1 = __builtin_amdgcn_mfma_f32_16x16x16f16(
                        wha[t][1][1], hb1, n1, 0, 0, 0);
#pragma unroll
                    for (int j = 0; j < 4; ++j) {
                        hb0[j] = (f16)fmaxf(n0[j], 0.f);
                        hb1[j] = (f16)fmaxf(n1[j], 0.f);
                    }
                }

                // output layer + nontemporal store (L2-bypass; measured
                // faster than plain stores despite partial-sector writes)
                f32x4 o0 = __builtin_amdgcn_mfma_f32_16x16x16f16(
                    woa[0][0], hb0, zero, 0, 0, 0);
                o0 = __builtin_amdgcn_mfma_f32_16x16x16f16(
                    woa[0][1], hb1, o0, 0, 0, 0);
                f32x4 o1 = __builtin_amdgcn_mfma_f32_16x16x16f16(
                    woa[1][0], hb0, zero, 0, 0, 0);
                o1 = __builtin_amdgcn_mfma_f32_16x16x16f16(
                    woa[1][1], hb1, o1, 0, 0, 0);

                float* op = out + (size_t)(rowbase + 16 * c + b) * 24;
                __builtin_nontemporal_store(
                    o0, reinterpret_cast<f32x4*>(op + 4 * g));
                if (g < 2) {
                    __builtin_nontemporal_store(
                        o1, reinterpret_cast<f32x4*>(op + 16 + 4 * g));
                }
            }
        }
    }

    // ---- tail rows (B % 32 != 0; unused for B = 1M) ----
    if (blockIdx.x == 0 && wid == 0) {
        for (int row = (ntiles << 5) + lane; row < B; row += 64) {
            float h[32];
#pragma unroll
            for (int j = 0; j < 32; ++j) h[j] = 0.f;
            const float* __restrict__ xr = x + (size_t)row * 64;
            for (int k = 0; k < 64; ++k) {
                float xv = xr[k];
#pragma unroll
                for (int j = 0; j < 32; ++j)
                    h[j] = fmaf(xv, Win[k * 32 + j], h[j]);
            }
#pragma unroll
            for (int j = 0; j < 32; ++j) h[j] = fmaxf(h[j], 0.f);
            for (int t = 0; t < 4; ++t) {
                float hn[32];
                for (int j = 0; j < 32; ++j) {
                    float acc = 0.f;
                    int blk = j >> 3;
                    for (int k = 0; k < 8; ++k)
                        acc = fmaf(h[blk * 8 + k],
                                   Wh[t * 1024 + (blk * 8 + k) * 32 + j], acc);
                    hn[j] = fmaxf(acc, 0.f);
                }
                for (int j = 0; j < 32; ++j) h[j] = hn[j];
            }
            for (int cth = 0; cth < 24; ++cth) {
                int i8 = cth / 3;
                float acc = 0.f;
                for (int s = 0; s < 4; ++s)
                    acc = fmaf(h[4 * i8 + s], Wout[(4 * i8 + s) * 24 + cth], acc);
                out[(size_t)row * 24 + cth] = acc;
            }
        }
    }
}

extern "C" void kernel_launch(void* const* d_in, const int* in_sizes, int n_in,
                              void* d_out, int out_size, void* d_ws, size_t ws_size,
                              hipStream_t stream)
{
    const float* x    = (const float*)d_in[0];  // [B,64]
    const float* Win  = (const float*)d_in[1];  // [64,32]
    const float* Wh   = (const float*)d_in[2];  // [4,32,32]
    const float* Wout = (const float*)d_in[3];  // [32,24]
    float* out        = (float*)d_out;          // [B,24]
    f16* ws           = (f16*)d_ws;

    int B = in_sizes[0] / 64;

    repack_kernel<<<(WS_TOT + 255) / 256, 256, 0, stream>>>(Win, Wh, Wout, ws);

    bd_mlp_kernel<<<1024, 256, 0, stream>>>(x, ws, Win, Wh, Wout, out, B);
}